// Round 17
// baseline (392.540 us; speedup 1.0000x reference)
//
#include <hip/hip_runtime.h>

typedef __bf16 bf16;
typedef __bf16 bf16x4 __attribute__((ext_vector_type(4)));
typedef __bf16 bf16x8 __attribute__((ext_vector_type(8)));
typedef short s16x4 __attribute__((ext_vector_type(4)));
typedef float f32x4 __attribute__((ext_vector_type(4)));

static constexpr int NB = 4;       // batch
static constexpr int NS = 2048;    // seq
static constexpr int ND = 1024;    // model dim
static constexpr int NH = 16;      // heads
static constexpr int HD = 64;      // head dim
static constexpr float QSCALE = 0.18033688011112042f;  // log2(e)/sqrt(64)

// async global->LDS, 16B per lane; LDS dest = wave-uniform base + lane*16
#define GL16(g, l)                                                             \
    __builtin_amdgcn_global_load_lds(                                          \
        (const __attribute__((address_space(1))) void*)(g),                    \
        (__attribute__((address_space(3))) void*)(l), 16, 0, 0)

static __device__ __forceinline__ unsigned pk2(float a, float b) {
    union { __bf16 h[2]; unsigned u; } t;
    t.h[0] = (__bf16)a; t.h[1] = (__bf16)b;
    return t.u;
}

// ---------------- convert f32 -> bf16 (vectorized) ----------------
__global__ void k_conv(const float* __restrict__ in, bf16* __restrict__ out, int n) {
    int i = (blockIdx.x * blockDim.x + threadIdx.x) * 4;
    if (i < n) {
        float4 v = *reinterpret_cast<const float4*>(in + i);
        bf16* o = out + i;
        o[0] = (bf16)v.x; o[1] = (bf16)v.y; o[2] = (bf16)v.z; o[3] = (bf16)v.w;
    }
}

// ------- transpose + convert: in[K][N] f32 -> out[N][K] bf16, full-line out ---
__global__ void k_transconv(const float* __restrict__ in, bf16* __restrict__ out,
                            int K, int N) {
    __shared__ float tile[64][33];
    int k0 = blockIdx.y * 64, n0 = blockIdx.x * 32;
    int tx = threadIdx.x, ty = threadIdx.y;  // block (32,8)
#pragma unroll
    for (int i = 0; i < 8; ++i)
        tile[ty + 8 * i][tx] = in[(long)(k0 + ty + 8 * i) * N + n0 + tx];
    __syncthreads();
    int t = ty * 32 + tx;
    int row = t >> 3;            // n-local 0..31
    int col8 = (t & 7) * 8;      // k-local chunk
    bf16x8 v;
#pragma unroll
    for (int c = 0; c < 8; ++c) v[c] = (bf16)tile[col8 + c][row];
    *reinterpret_cast<bf16x8*>(&out[(long)(n0 + row) * K + k0 + col8]) = v;
}

// ======== merged QKV GEMM, 128x128, 2-phase + counted vmcnt ==================
// All blocks: swapped mfma (lane holds s-row fixed, 4 consecutive n-cols).
// Q/K blocks (cols<2048): full-line [s][hd] store (Q scaled).
// V blocks  (cols>=2048): scalar-gather transpose from eb with key-permutation
//   pos 32p+8l+4h+i <- key 32p+16h+4l+i, full-line [d][s] store to Vt.
__global__ __launch_bounds__(256, 2) void k_gemmQKV(
    const bf16* __restrict__ A, const bf16* __restrict__ Bt,
    const float* __restrict__ bias,
    bf16* __restrict__ Qb, bf16* __restrict__ Kb, bf16* __restrict__ Vt,
    int Kd)
{
    constexpr int BM = 128, BN = 128, BK = 64;
    __shared__ __align__(16) bf16 As[2][BM * BK];
    __shared__ __align__(16) bf16 Bs[2][BN * BK];

    const int t = threadIdx.x;
    const int wid = t >> 6, lane = t & 63;
    const int wm = wid >> 1, wn = wid & 1;
    const int m0 = blockIdx.y * BM, n0 = blockIdx.x * BN;
    const int lrow = lane & 15, lhi = lane >> 4;

    const int srow0 = wid * 32 + (lane >> 3);
    const int scol = ((lane & 7) ^ (lane >> 3)) * 8;
    const bf16* ag = A + (long)(m0 + srow0) * Kd + scol;
    const bf16* bg = Bt + (long)(n0 + srow0) * Kd + scol;

    auto STAGE = [&](int buf_, int k0_) {
#pragma unroll
        for (int c = 0; c < 4; ++c) {
            GL16(ag + (long)(c * 8) * Kd + k0_, &As[buf_][(wid * 32 + c * 8) * BK]);
            GL16(bg + (long)(c * 8) * Kd + k0_, &Bs[buf_][(wid * 32 + c * 8) * BK]);
        }
    };

    f32x4 acc[4][4] = {};
    const int nt = Kd >> 6;
    const int swzr = (lrow & 7) << 4;
    int co[2];
#pragma unroll
    for (int kk = 0; kk < 2; ++kk)
        co[kk] = ((kk * 64 + lhi * 16) ^ swzr) >> 1;

    STAGE(0, 0);
    int cur = 0;
    for (int tix = 0; tix < nt; ++tix) {
        if (tix + 1 < nt) {
            STAGE(cur ^ 1, (tix + 1) * BK);
            asm volatile("s_waitcnt vmcnt(8)" ::: "memory");
        } else {
            asm volatile("s_waitcnt vmcnt(0)" ::: "memory");
        }
        __builtin_amdgcn_s_barrier();
        __builtin_amdgcn_sched_barrier(0);

        bf16x8 af[2][4], bfr[2][4];
#pragma unroll
        for (int kk = 0; kk < 2; ++kk)
#pragma unroll
            for (int i = 0; i < 4; ++i) {
                af[kk][i]  = *reinterpret_cast<const bf16x8*>(
                    &As[cur][(wm * 64 + i * 16 + lrow) * BK + co[kk]]);
                bfr[kk][i] = *reinterpret_cast<const bf16x8*>(
                    &Bs[cur][(wn * 64 + i * 16 + lrow) * BK + co[kk]]);
            }
        __builtin_amdgcn_s_setprio(1);
#pragma unroll
        for (int kk = 0; kk < 2; ++kk)
#pragma unroll
            for (int i = 0; i < 4; ++i)
#pragma unroll
                for (int j = 0; j < 4; ++j)
                    acc[i][j] = __builtin_amdgcn_mfma_f32_16x16x32_bf16(
                        bfr[kk][j], af[kk][i], acc[i][j], 0, 0, 0);
        __builtin_amdgcn_s_setprio(0);
        __builtin_amdgcn_s_barrier();   // also covers epilogue LDS reuse
        cur ^= 1;
    }

    const int colbase = n0 + wn * 64;
    const int which = colbase >> 10;          // 0:Q 1:K 2:V
    const bool isQ = (which == 0);

    // common eb-write: wave-private 64(s) x 64(n) swizzled tile
    bf16* eb = (bf16*)As + wid * 4096;
#pragma unroll
    for (int j = 0; j < 4; ++j) {
        f32x4 bv = *reinterpret_cast<const f32x4*>(&bias[colbase + j * 16 + 4 * lhi]);
#pragma unroll
        for (int i = 0; i < 4; ++i) {
            int srt = i * 16 + lrow;
            bf16x4 pk;
#pragma unroll
            for (int r = 0; r < 4; ++r) {
                float v = acc[i][j][r] + bv[r];
                pk[r] = (bf16)(isQ ? v * QSCALE : v);
            }
            *reinterpret_cast<bf16x4*>(
                reinterpret_cast<char*>(eb) + srt * 128 +
                (((j * 16 + 4 * lhi) * 2) ^ ((srt & 7) << 4))) = pk;
        }
    }
    const int h = (colbase & 1023) >> 6;
    const int mrow = m0 + wm * 64;
    const int bb = mrow >> 11, s0 = mrow & 2047;
    const long bh = (long)bb * NH + h;

    if (which < 2) {
        bf16* Ob = isQ ? Qb : Kb;
#pragma unroll
        for (int it = 0; it < 8; ++it) {
            int rt = it * 8 + (lane >> 3);
            bf16x8 v = *reinterpret_cast<const bf16x8*>(
                reinterpret_cast<char*>(eb) + rt * 128 +
                (((lane & 7) * 16) ^ ((rt & 7) << 4)));
            int s = s0 + rt;     // mrow&2047 + rt; batch from bb
            *reinterpret_cast<bf16x8*>(&Ob[(bh * NS + s) * HD + (lane & 7) * 8]) = v;
        }
    } else {
        // V: gather-transpose with key permutation, full-line [d][s] store
        const int p = (lane & 7) >> 2;         // pos0>>5
        const int l4 = (lane & 3) * 4;
        const int pos0 = (lane & 7) * 8;
#pragma unroll
        for (int it = 0; it < 8; ++it) {
            int dt = it * 8 + (lane >> 3);
            bf16x8 v;
#pragma unroll
            for (int j = 0; j < 8; ++j) {
                int k = 32 * p + 16 * (j >> 2) + l4 + (j & 3);   // source s-row
                v[j] = *reinterpret_cast<const bf16*>(
                    reinterpret_cast<char*>(eb) + k * 128 +
                    ((dt * 2) ^ ((k & 7) << 4)));
            }
            *reinterpret_cast<bf16x8*>(&Vt[(bh * HD + dt) * NS + s0 + pos0]) = v;
        }
    }
}

// ======== out-GEMM, 128x128, 2-phase + counted vmcnt, f32 full-line out ======
__global__ __launch_bounds__(256, 2) void k_gemmO(
    const bf16* __restrict__ A, const bf16* __restrict__ Bt,
    const float* __restrict__ bias, float* __restrict__ O, int Kd)
{
    constexpr int BM = 128, BN = 128, BK = 64;
    __shared__ __align__(16) bf16 As[2][BM * BK];
    __shared__ __align__(16) bf16 Bs[2][BN * BK];

    const int t = threadIdx.x;
    const int wid = t >> 6, lane = t & 63;
    const int wm = wid >> 1, wn = wid & 1;
    const int m0 = blockIdx.y * BM, n0 = blockIdx.x * BN;
    const int lrow = lane & 15, lhi = lane >> 4;

    const int srow0 = wid * 32 + (lane >> 3);
    const int scol = ((lane & 7) ^ (lane >> 3)) * 8;
    const bf16* ag = A + (long)(m0 + srow0) * Kd + scol;
    const bf16* bg = Bt + (long)(n0 + srow0) * Kd + scol;

    auto STAGE = [&](int buf_, int k0_) {
#pragma unroll
        for (int c = 0; c < 4; ++c) {
            GL16(ag + (long)(c * 8) * Kd + k0_, &As[buf_][(wid * 32 + c * 8) * BK]);
            GL16(bg + (long)(c * 8) * Kd + k0_, &Bs[buf_][(wid * 32 + c * 8) * BK]);
        }
    };

    f32x4 acc[4][4] = {};
    const int nt = Kd >> 6;
    const int swzr = (lrow & 7) << 4;
    int co[2];
#pragma unroll
    for (int kk = 0; kk < 2; ++kk)
        co[kk] = ((kk * 64 + lhi * 16) ^ swzr) >> 1;

    STAGE(0, 0);
    int cur = 0;
    for (int tix = 0; tix < nt; ++tix) {
        if (tix + 1 < nt) {
            STAGE(cur ^ 1, (tix + 1) * BK);
            asm volatile("s_waitcnt vmcnt(8)" ::: "memory");
        } else {
            asm volatile("s_waitcnt vmcnt(0)" ::: "memory");
        }
        __builtin_amdgcn_s_barrier();
        __builtin_amdgcn_sched_barrier(0);

        bf16x8 af[2][4], bfr[2][4];
#pragma unroll
        for (int kk = 0; kk < 2; ++kk)
#pragma unroll
            for (int i = 0; i < 4; ++i) {
                af[kk][i]  = *reinterpret_cast<const bf16x8*>(
                    &As[cur][(wm * 64 + i * 16 + lrow) * BK + co[kk]]);
                bfr[kk][i] = *reinterpret_cast<const bf16x8*>(
                    &Bs[cur][(wn * 64 + i * 16 + lrow) * BK + co[kk]]);
            }
        __builtin_amdgcn_s_setprio(1);
#pragma unroll
        for (int kk = 0; kk < 2; ++kk)
#pragma unroll
            for (int i = 0; i < 4; ++i)
#pragma unroll
                for (int j = 0; j < 4; ++j)
                    acc[i][j] = __builtin_amdgcn_mfma_f32_16x16x32_bf16(
                        bfr[kk][j], af[kk][i], acc[i][j], 0, 0, 0);
        __builtin_amdgcn_s_setprio(0);
        __builtin_amdgcn_s_barrier();
        cur ^= 1;
    }

    const int colbase = n0 + wn * 64;
    float* ef = (float*)As + wid * 2048;   // wave-private 32x64 f32 (8 KB)
#pragma unroll
    for (int half = 0; half < 2; ++half) {
#pragma unroll
        for (int i2 = 0; i2 < 2; ++i2) {
            int i = half * 2 + i2;
            int srt = i2 * 16 + lrow;
#pragma unroll
            for (int j = 0; j < 4; ++j) {
                f32x4 bv = *reinterpret_cast<const f32x4*>(
                    &bias[colbase + j * 16 + 4 * lhi]);
                f32x4 v = acc[i][j] + bv;
                *reinterpret_cast<f32x4*>(
                    reinterpret_cast<char*>(ef) + srt * 256 +
                    (((j * 16 + 4 * lhi) * 4) ^ ((srt & 7) << 4))) = v;
            }
        }
#pragma unroll
        for (int it = 0; it < 8; ++it) {
            int rt = it * 4 + (lane >> 4);
            f32x4 v = *reinterpret_cast<const f32x4*>(
                reinterpret_cast<char*>(ef) + rt * 256 +
                (((lane & 15) * 16) ^ ((rt & 7) << 4)));
            int row = m0 + wm * 64 + half * 32 + rt;
            *reinterpret_cast<f32x4*>(
                &O[(long)row * 1024 + colbase + (lane & 15) * 4]) = v;
        }
        asm volatile("" ::: "memory");   // half0 reads before half1 writes
    }
}

// ---------------- flash attention v10: KB=128 (two-half), in-register P ------
// 8 waves, 256 q/block, 32 q/wave. Swapped QK^T; PV via K=16 MFMA on permuted
// Vt (P never leaves registers). 128-key tiles processed as two 64-key halves
// inside one barrier window -> barriers/tile halved. LDS 64 KB.
__global__ __launch_bounds__(512, 4) void k_attn(
    const bf16* __restrict__ Qb, const bf16* __restrict__ Kb,
    const bf16* __restrict__ Vt, bf16* __restrict__ Ao)
{
    constexpr int KB = 128;
    constexpr int NT = NS / KB;   // 16 tiles
    __shared__ __align__(16) bf16 Ks[2][KB * HD];      // 2 x 16 KB, row=key
    __shared__ __align__(16) bf16 Vs[2][2][64 * 64];   // 2 x 2 x 8 KB, row=d

    const int t = threadIdx.x;
    const int wid = t >> 6, lane = t & 63;
    const int lrow = lane & 15, lhi = lane >> 4;

    // bijective XCD swizzle: 512 blocks, 8 XCDs, 64 contiguous per XCD
    const int flat = blockIdx.y * gridDim.x + blockIdx.x;
    const int n = (flat & 7) * 64 + (flat >> 3);
    const int bh = n >> 3;
    const int qw = (n & 7) * 256 + wid * 32;   // wave's 32 q rows

    const bf16* Qg = Qb + ((long)bh * NS + qw) * HD;
    const bf16* Kg = Kb + (long)bh * NS * HD;
    const bf16* Vg = Vt + (long)bh * HD * NS;

    bf16x8 qf[2][2];
#pragma unroll
    for (int qfr = 0; qfr < 2; ++qfr)
#pragma unroll
        for (int c = 0; c < 2; ++c)
            qf[qfr][c] = *reinterpret_cast<const bf16x8*>(
                Qg + (long)(qfr * 16 + lrow) * HD + c * 32 + lhi * 8);

    f32x4 of[2][4] = {};
    float lsum[2] = {0.f, 0.f};

    const int gsr = lane >> 3;
    const int gsc = ((lane & 7) ^ gsr) * 8;
    auto STAGE = [&](int buf, int kb) {
        GL16(Kg + (long)(kb + wid * 16 + gsr) * HD + gsc,     &Ks[buf][(wid * 16) * 64]);
        GL16(Kg + (long)(kb + wid * 16 + 8 + gsr) * HD + gsc, &Ks[buf][(wid * 16 + 8) * 64]);
        GL16(Vg + (long)(wid * 8 + gsr) * NS + kb + gsc,      &Vs[buf][0][(wid * 8) * 64]);
        GL16(Vg + (long)(wid * 8 + gsr) * NS + kb + 64 + gsc, &Vs[buf][1][(wid * 8) * 64]);
    };

    const int rsw = (lrow & 7) << 4;

    auto COMPUTE = [&](int b_, int ho) {
        f32x4 st[2][4] = {};
        __builtin_amdgcn_s_setprio(1);
#pragma unroll
        for (int j = 0; j < 4; ++j)
#pragma unroll
            for (int c = 0; c < 2; ++c) {
                bf16x8 kf = *reinterpret_cast<const bf16x8*>(
                    &Ks[b_][(ho * 64 + j * 16 + lrow) * 64 +
                            (((c * 64 + lhi * 16) ^ rsw) >> 1)]);
#pragma unroll
                for (int qfr = 0; qfr < 2; ++qfr)
                    st[qfr][j] = __builtin_amdgcn_mfma_f32_16x16x32_bf16(
                        kf, qf[qfr][c], st[qfr][j], 0, 0, 0);
            }
        __builtin_amdgcn_s_setprio(0);

        union { unsigned u[2]; s16x4 s; } pj[2][4];
#pragma unroll
        for (int qfr = 0; qfr < 2; ++qfr)
#pragma unroll
            for (int j = 0; j < 4; ++j) {
                float e0 = __builtin_amdgcn_exp2f(st[qfr][j][0]);
                float e1 = __builtin_amdgcn_exp2f(st[qfr][j][1]);
                float e2 = __builtin_amdgcn_exp2f(st[qfr][j][2]);
                float e3 = __builtin_amdgcn_exp2f(st[qfr][j][3]);
                lsum[qfr] += (e0 + e1) + (e2 + e3);
                pj[qfr][j].u[0] = pk2(e0, e1);
                pj[qfr][j].u[1] = pk2(e2, e3);
            }

        __builtin_amdgcn_s_setprio(1);
#pragma unroll
        for (int p = 0; p < 2; ++p)
#pragma unroll
            for (int f = 0; f < 4; ++f) {
                union { bf16x8 v; s16x4 h[2]; } vf;
                vf.v = *reinterpret_cast<const bf16x8*>(
                    &Vs[b_][ho][(f * 16 + lrow) * 64 +
                                (((p * 64 + lhi * 16) ^ rsw) >> 1)]);
#pragma unroll
                for (int qfr = 0; qfr < 2; ++qfr) {
                    of[qfr][f] = __builtin_amdgcn_mfma_f32_16x16x16bf16_1k(
                        vf.h[0], pj[qfr][2 * p].s, of[qfr][f], 0, 0, 0);
                    of[qfr][f] = __builtin_amdgcn_mfma_f32_16x16x16bf16_1k(
                        vf.h[1], pj[qfr][2 * p + 1].s, of[qfr][f], 0, 0, 0);
                }
            }
        __builtin_amdgcn_s_setprio(0);
    };

    STAGE(0, 0);
    int cur = 0;
    for (int it = 0; it < NT; ++it) {
        if (it + 1 < NT) {
            STAGE(cur ^ 1, (it + 1) * KB);
            asm volatile("s_waitcnt vmcnt(4)" ::: "memory");  // cur's 4 landed
        } else {
            asm volatile("s_waitcnt vmcnt(0)" ::: "memory");
        }
        __builtin_amdgcn_s_barrier();
        __builtin_amdgcn_sched_barrier(0);
        COMPUTE(cur, 0);
        COMPUTE(cur, 1);
        __builtin_amdgcn_s_barrier();   // reads of cur done -> overwrite ok
        cur ^= 1;
    }

    // l reduce over lhi groups -> every lane holds l(q = lrow) per fragment
#pragma unroll
    for (int qfr = 0; qfr < 2; ++qfr) {
        lsum[qfr] += __shfl_xor(lsum[qfr], 16);
        lsum[qfr] += __shfl_xor(lsum[qfr], 32);
    }

    // epilogue: wave-private 32(s) x 64(d) transpose; waves 0-3 in Ks, 4-7 in Vs
    bf16* eb = (wid < 4) ? ((bf16*)Ks + wid * 2048)
                         : ((bf16*)Vs + (wid - 4) * 2048);
#pragma unroll
    for (int qfr = 0; qfr < 2; ++qfr) {
        float inv = 1.0f / lsum[qfr];
        int srt = qfr * 16 + lrow;
#pragma unroll
        for (int f = 0; f < 4; ++f) {
            bf16x4 pk;
#pragma unroll
            for (int r = 0; r < 4; ++r) pk[r] = (bf16)(of[qfr][f][r] * inv);
            *reinterpret_cast<bf16x4*>(
                reinterpret_cast<char*>(eb) + srt * 128 +
                (((f * 16 + 4 * lhi) * 2) ^ ((srt & 7) << 4))) = pk;
        }
    }
    const int bb = bh >> 4, h = bh & 15;
#pragma unroll
    for (int it = 0; it < 4; ++it) {
        int rt = it * 8 + (lane >> 3);
        bf16x8 v = *reinterpret_cast<const bf16x8*>(
            reinterpret_cast<char*>(eb) + rt * 128 +
            (((lane & 7) * 16) ^ ((rt & 7) << 4)));
        int s = qw + rt;
        *reinterpret_cast<bf16x8*>(
            &Ao[((long)bb * NS + s) * ND + h * HD + (lane & 7) * 8]) = v;
    }
}

// ---------------- launch ----------------
extern "C" void kernel_launch(void* const* d_in, const int* in_sizes, int n_in,
                              void* d_out, int out_size, void* d_ws, size_t ws_size,
                              hipStream_t stream) {
    const float* x    = (const float*)d_in[0];
    const float* Wqkv = (const float*)d_in[1];
    const float* bqkv = (const float*)d_in[2];
    const float* Wout = (const float*)d_in[3];
    const float* bout = (const float*)d_in[4];
    float* out = (float*)d_out;

    char* ws = (char*)d_ws;
    bf16* Xb  = (bf16*)(ws);                         // 16.78 MB
    bf16* Wqt = (bf16*)(ws + 16777216);              //  6.29 MB
    bf16* Wot = (bf16*)(ws + 23068672);              //  2.10 MB
    bf16* Qb  = (bf16*)(ws + 25165824);              // 16.78 MB
    bf16* Kb  = (bf16*)(ws + 41943040);              // 16.78 MB
    bf16* Vt  = (bf16*)(ws + 58720256);              // 16.78 MB
    bf16* Ab  = (bf16*)(ws + 75497472);              // 16.78 MB  (total ~92 MB)

    k_conv<<<dim3(8192), dim3(256), 0, stream>>>(x, Xb, NB * NS * ND);
    k_transconv<<<dim3(96, 16), dim3(32, 8), 0, stream>>>(Wqkv, Wqt, ND, 3 * ND);
    k_transconv<<<dim3(32, 16), dim3(32, 8), 0, stream>>>(Wout, Wot, ND, ND);

    // merged QKV producer: 1536 blocks = 3 exact generations at 2/CU
    k_gemmQKV<<<dim3(24, 64), dim3(256), 0, stream>>>(
        Xb, Wqt, bqkv, Qb, Kb, Vt, ND);

    k_attn<<<dim3(8, 64), dim3(512), 0, stream>>>(Qb, Kb, Vt, Ab);

    k_gemmO<<<dim3(8, 64), dim3(256), 0, stream>>>(
        Ab, Wot, bout, out, ND);
}

// Round 18
// 191.189 us; speedup vs baseline: 2.0531x; 2.0531x over previous
//
#include <hip/hip_runtime.h>

typedef __bf16 bf16;
typedef __bf16 bf16x4 __attribute__((ext_vector_type(4)));
typedef __bf16 bf16x8 __attribute__((ext_vector_type(8)));
typedef short s16x4 __attribute__((ext_vector_type(4)));
typedef float f32x4 __attribute__((ext_vector_type(4)));

static constexpr int NB = 4;       // batch
static constexpr int NS = 2048;    // seq
static constexpr int ND = 1024;    // model dim
static constexpr int NH = 16;      // heads
static constexpr int HD = 64;      // head dim
static constexpr float QSCALE = 0.18033688011112042f;  // log2(e)/sqrt(64)

// async global->LDS, 16B per lane; LDS dest = wave-uniform base + lane*16
#define GL16(g, l)                                                             \
    __builtin_amdgcn_global_load_lds(                                          \
        (const __attribute__((address_space(1))) void*)(g),                    \
        (__attribute__((address_space(3))) void*)(l), 16, 0, 0)

static __device__ __forceinline__ unsigned pk2(float a, float b) {
    union { __bf16 h[2]; unsigned u; } t;
    t.h[0] = (__bf16)a; t.h[1] = (__bf16)b;
    return t.u;
}

// ---------------- convert f32 -> bf16 (vectorized) ----------------
__global__ void k_conv(const float* __restrict__ in, bf16* __restrict__ out, int n) {
    int i = (blockIdx.x * blockDim.x + threadIdx.x) * 4;
    if (i < n) {
        float4 v = *reinterpret_cast<const float4*>(in + i);
        bf16* o = out + i;
        o[0] = (bf16)v.x; o[1] = (bf16)v.y; o[2] = (bf16)v.z; o[3] = (bf16)v.w;
    }
}

// ------- transpose + convert: in[K][N] f32 -> out[N][K] bf16, full-line out ---
__global__ void k_transconv(const float* __restrict__ in, bf16* __restrict__ out,
                            int K, int N) {
    __shared__ float tile[64][33];
    int k0 = blockIdx.y * 64, n0 = blockIdx.x * 32;
    int tx = threadIdx.x, ty = threadIdx.y;  // block (32,8)
#pragma unroll
    for (int i = 0; i < 8; ++i)
        tile[ty + 8 * i][tx] = in[(long)(k0 + ty + 8 * i) * N + n0 + tx];
    __syncthreads();
    int t = ty * 32 + tx;
    int row = t >> 3;            // n-local 0..31
    int col8 = (t & 7) * 8;      // k-local chunk
    bf16x8 v;
#pragma unroll
    for (int c = 0; c < 8; ++c) v[c] = (bf16)tile[col8 + c][row];
    *reinterpret_cast<bf16x8*>(&out[(long)(n0 + row) * K + k0 + col8]) = v;
}

// ======== merged QKV GEMM, 128x128, 2-phase + counted vmcnt ==================
// All blocks: swapped mfma (lane holds s-row fixed, 4 consecutive n-cols).
// Q/K blocks (cols<2048): full-line [s][hd] store (Q scaled).
// V blocks  (cols>=2048): scalar-gather transpose from eb with key-permutation
//   pos 32p+8l+4h+i <- key 32p+16h+4l+i, full-line [d][s] store to Vt.
__global__ __launch_bounds__(256, 2) void k_gemmQKV(
    const bf16* __restrict__ A, const bf16* __restrict__ Bt,
    const float* __restrict__ bias,
    bf16* __restrict__ Qb, bf16* __restrict__ Kb, bf16* __restrict__ Vt,
    int Kd)
{
    constexpr int BM = 128, BN = 128, BK = 64;
    __shared__ __align__(16) bf16 As[2][BM * BK];
    __shared__ __align__(16) bf16 Bs[2][BN * BK];

    const int t = threadIdx.x;
    const int wid = t >> 6, lane = t & 63;
    const int wm = wid >> 1, wn = wid & 1;
    const int m0 = blockIdx.y * BM, n0 = blockIdx.x * BN;
    const int lrow = lane & 15, lhi = lane >> 4;

    const int srow0 = wid * 32 + (lane >> 3);
    const int scol = ((lane & 7) ^ (lane >> 3)) * 8;
    const bf16* ag = A + (long)(m0 + srow0) * Kd + scol;
    const bf16* bg = Bt + (long)(n0 + srow0) * Kd + scol;

    auto STAGE = [&](int buf_, int k0_) {
#pragma unroll
        for (int c = 0; c < 4; ++c) {
            GL16(ag + (long)(c * 8) * Kd + k0_, &As[buf_][(wid * 32 + c * 8) * BK]);
            GL16(bg + (long)(c * 8) * Kd + k0_, &Bs[buf_][(wid * 32 + c * 8) * BK]);
        }
    };

    f32x4 acc[4][4] = {};
    const int nt = Kd >> 6;
    const int swzr = (lrow & 7) << 4;
    int co[2];
#pragma unroll
    for (int kk = 0; kk < 2; ++kk)
        co[kk] = ((kk * 64 + lhi * 16) ^ swzr) >> 1;

    STAGE(0, 0);
    int cur = 0;
    for (int tix = 0; tix < nt; ++tix) {
        if (tix + 1 < nt) {
            STAGE(cur ^ 1, (tix + 1) * BK);
            asm volatile("s_waitcnt vmcnt(8)" ::: "memory");
        } else {
            asm volatile("s_waitcnt vmcnt(0)" ::: "memory");
        }
        __builtin_amdgcn_s_barrier();
        __builtin_amdgcn_sched_barrier(0);

        bf16x8 af[2][4], bfr[2][4];
#pragma unroll
        for (int kk = 0; kk < 2; ++kk)
#pragma unroll
            for (int i = 0; i < 4; ++i) {
                af[kk][i]  = *reinterpret_cast<const bf16x8*>(
                    &As[cur][(wm * 64 + i * 16 + lrow) * BK + co[kk]]);
                bfr[kk][i] = *reinterpret_cast<const bf16x8*>(
                    &Bs[cur][(wn * 64 + i * 16 + lrow) * BK + co[kk]]);
            }
        __builtin_amdgcn_s_setprio(1);
#pragma unroll
        for (int kk = 0; kk < 2; ++kk)
#pragma unroll
            for (int i = 0; i < 4; ++i)
#pragma unroll
                for (int j = 0; j < 4; ++j)
                    acc[i][j] = __builtin_amdgcn_mfma_f32_16x16x32_bf16(
                        bfr[kk][j], af[kk][i], acc[i][j], 0, 0, 0);
        __builtin_amdgcn_s_setprio(0);
        __builtin_amdgcn_s_barrier();   // also covers epilogue LDS reuse
        cur ^= 1;
    }

    const int colbase = n0 + wn * 64;
    const int which = colbase >> 10;          // 0:Q 1:K 2:V
    const bool isQ = (which == 0);

    // common eb-write: wave-private 64(s) x 64(n) swizzled tile
    bf16* eb = (bf16*)As + wid * 4096;
#pragma unroll
    for (int j = 0; j < 4; ++j) {
        f32x4 bv = *reinterpret_cast<const f32x4*>(&bias[colbase + j * 16 + 4 * lhi]);
#pragma unroll
        for (int i = 0; i < 4; ++i) {
            int srt = i * 16 + lrow;
            bf16x4 pk;
#pragma unroll
            for (int r = 0; r < 4; ++r) {
                float v = acc[i][j][r] + bv[r];
                pk[r] = (bf16)(isQ ? v * QSCALE : v);
            }
            *reinterpret_cast<bf16x4*>(
                reinterpret_cast<char*>(eb) + srt * 128 +
                (((j * 16 + 4 * lhi) * 2) ^ ((srt & 7) << 4))) = pk;
        }
    }
    const int h = (colbase & 1023) >> 6;
    const int mrow = m0 + wm * 64;
    const int bb = mrow >> 11, s0 = mrow & 2047;
    const long bh = (long)bb * NH + h;

    if (which < 2) {
        bf16* Ob = isQ ? Qb : Kb;
#pragma unroll
        for (int it = 0; it < 8; ++it) {
            int rt = it * 8 + (lane >> 3);
            bf16x8 v = *reinterpret_cast<const bf16x8*>(
                reinterpret_cast<char*>(eb) + rt * 128 +
                (((lane & 7) * 16) ^ ((rt & 7) << 4)));
            int s = s0 + rt;
            *reinterpret_cast<bf16x8*>(&Ob[(bh * NS + s) * HD + (lane & 7) * 8]) = v;
        }
    } else {
        // V: gather-transpose with key permutation, full-line [d][s] store
        const int p = (lane & 7) >> 2;
        const int l4 = (lane & 3) * 4;
        const int pos0 = (lane & 7) * 8;
#pragma unroll
        for (int it = 0; it < 8; ++it) {
            int dt = it * 8 + (lane >> 3);
            bf16x8 v;
#pragma unroll
            for (int j = 0; j < 8; ++j) {
                int k = 32 * p + 16 * (j >> 2) + l4 + (j & 3);   // source s-row
                v[j] = *reinterpret_cast<const bf16*>(
                    reinterpret_cast<char*>(eb) + k * 128 +
                    ((dt * 2) ^ ((k & 7) << 4)));
            }
            *reinterpret_cast<bf16x8*>(&Vt[(bh * HD + dt) * NS + s0 + pos0]) = v;
        }
    }
}

// ======== out-GEMM, 128x128, 2-phase + counted vmcnt, f32 full-line out ======
__global__ __launch_bounds__(256, 2) void k_gemmO(
    const bf16* __restrict__ A, const bf16* __restrict__ Bt,
    const float* __restrict__ bias, float* __restrict__ O, int Kd)
{
    constexpr int BM = 128, BN = 128, BK = 64;
    __shared__ __align__(16) bf16 As[2][BM * BK];
    __shared__ __align__(16) bf16 Bs[2][BN * BK];

    const int t = threadIdx.x;
    const int wid = t >> 6, lane = t & 63;
    const int wm = wid >> 1, wn = wid & 1;
    const int m0 = blockIdx.y * BM, n0 = blockIdx.x * BN;
    const int lrow = lane & 15, lhi = lane >> 4;

    const int srow0 = wid * 32 + (lane >> 3);
    const int scol = ((lane & 7) ^ (lane >> 3)) * 8;
    const bf16* ag = A + (long)(m0 + srow0) * Kd + scol;
    const bf16* bg = Bt + (long)(n0 + srow0) * Kd + scol;

    auto STAGE = [&](int buf_, int k0_) {
#pragma unroll
        for (int c = 0; c < 4; ++c) {
            GL16(ag + (long)(c * 8) * Kd + k0_, &As[buf_][(wid * 32 + c * 8) * BK]);
            GL16(bg + (long)(c * 8) * Kd + k0_, &Bs[buf_][(wid * 32 + c * 8) * BK]);
        }
    };

    f32x4 acc[4][4] = {};
    const int nt = Kd >> 6;
    const int swzr = (lrow & 7) << 4;
    int co[2];
#pragma unroll
    for (int kk = 0; kk < 2; ++kk)
        co[kk] = ((kk * 64 + lhi * 16) ^ swzr) >> 1;

    STAGE(0, 0);
    int cur = 0;
    for (int tix = 0; tix < nt; ++tix) {
        if (tix + 1 < nt) {
            STAGE(cur ^ 1, (tix + 1) * BK);
            asm volatile("s_waitcnt vmcnt(8)" ::: "memory");
        } else {
            asm volatile("s_waitcnt vmcnt(0)" ::: "memory");
        }
        __builtin_amdgcn_s_barrier();
        __builtin_amdgcn_sched_barrier(0);

        bf16x8 af[2][4], bfr[2][4];
#pragma unroll
        for (int kk = 0; kk < 2; ++kk)
#pragma unroll
            for (int i = 0; i < 4; ++i) {
                af[kk][i]  = *reinterpret_cast<const bf16x8*>(
                    &As[cur][(wm * 64 + i * 16 + lrow) * BK + co[kk]]);
                bfr[kk][i] = *reinterpret_cast<const bf16x8*>(
                    &Bs[cur][(wn * 64 + i * 16 + lrow) * BK + co[kk]]);
            }
        __builtin_amdgcn_s_setprio(1);
#pragma unroll
        for (int kk = 0; kk < 2; ++kk)
#pragma unroll
            for (int i = 0; i < 4; ++i)
#pragma unroll
                for (int j = 0; j < 4; ++j)
                    acc[i][j] = __builtin_amdgcn_mfma_f32_16x16x32_bf16(
                        bfr[kk][j], af[kk][i], acc[i][j], 0, 0, 0);
        __builtin_amdgcn_s_setprio(0);
        __builtin_amdgcn_s_barrier();
        cur ^= 1;
    }

    const int colbase = n0 + wn * 64;
    float* ef = (float*)As + wid * 2048;   // wave-private 32x64 f32 (8 KB)
#pragma unroll
    for (int half = 0; half < 2; ++half) {
#pragma unroll
        for (int i2 = 0; i2 < 2; ++i2) {
            int i = half * 2 + i2;
            int srt = i2 * 16 + lrow;
#pragma unroll
            for (int j = 0; j < 4; ++j) {
                f32x4 bv = *reinterpret_cast<const f32x4*>(
                    &bias[colbase + j * 16 + 4 * lhi]);
                f32x4 v = acc[i][j] + bv;
                *reinterpret_cast<f32x4*>(
                    reinterpret_cast<char*>(ef) + srt * 256 +
                    (((j * 16 + 4 * lhi) * 4) ^ ((srt & 7) << 4))) = v;
            }
        }
#pragma unroll
        for (int it = 0; it < 8; ++it) {
            int rt = it * 4 + (lane >> 4);
            f32x4 v = *reinterpret_cast<const f32x4*>(
                reinterpret_cast<char*>(ef) + rt * 256 +
                (((lane & 15) * 16) ^ ((rt & 7) << 4)));
            int row = m0 + wm * 64 + half * 32 + rt;
            *reinterpret_cast<f32x4*>(
                &O[(long)row * 1024 + colbase + (lane & 15) * 4]) = v;
        }
        asm volatile("" ::: "memory");   // half0 reads before half1 writes
    }
}

// ---------------- flash attention v9 (r16 known-good): in-register P ---------
// 8 waves, 256 q/block, 32 q/wave, KB=64. Swapped QK^T D-layout (keys 4*lhi+r)
// IS the 16x16x16 B-operand k-grain -> P feeds PV directly from registers.
// Vt key-permuted so one conflict-free b128 read yields both s16x4 halves.
// LDS = K/V dbuf only (32 KB). Counted vmcnt(2) staging.
__global__ __launch_bounds__(512, 4) void k_attn(
    const bf16* __restrict__ Qb, const bf16* __restrict__ Kb,
    const bf16* __restrict__ Vt, bf16* __restrict__ Ao)
{
    constexpr int KB = 64;
    constexpr int NT = NS / KB;   // 32 tiles
    __shared__ __align__(16) bf16 Ks[2][KB * HD];   // 16 KB, row=key, swizzled
    __shared__ __align__(16) bf16 Vs[2][HD * KB];   // 16 KB, row=d,   swizzled

    const int t = threadIdx.x;
    const int wid = t >> 6, lane = t & 63;
    const int lrow = lane & 15, lhi = lane >> 4;

    // bijective XCD swizzle: 512 blocks, 8 XCDs, 64 contiguous per XCD
    const int flat = blockIdx.y * gridDim.x + blockIdx.x;
    const int n = (flat & 7) * 64 + (flat >> 3);
    const int bh = n >> 3;
    const int qw = (n & 7) * 256 + wid * 32;   // wave's 32 q rows

    const bf16* Qg = Qb + ((long)bh * NS + qw) * HD;
    const bf16* Kg = Kb + (long)bh * NS * HD;
    const bf16* Vg = Vt + (long)bh * HD * NS;

    bf16x8 qf[2][2];
#pragma unroll
    for (int qfr = 0; qfr < 2; ++qfr)
#pragma unroll
        for (int c = 0; c < 2; ++c)
            qf[qfr][c] = *reinterpret_cast<const bf16x8*>(
                Qg + (long)(qfr * 16 + lrow) * HD + c * 32 + lhi * 8);

    f32x4 of[2][4] = {};
    float lsum[2] = {0.f, 0.f};

    // staging: wave w covers K rows w*8..+8 and V rows w*8..+8
    const int gsr = lane >> 3;
    const int gsc = ((lane & 7) ^ gsr) * 8;
    const int rb = wid * 8;
    auto STAGE = [&](int buf, int kb) {
        GL16(Kg + (long)(kb + rb + gsr) * HD + gsc, &Ks[buf][rb * 64]);
        GL16(Vg + (long)(rb + gsr) * NS + kb + gsc, &Vs[buf][rb * 64]);
    };

    const int rsw = (lrow & 7) << 4;

    auto COMPUTE = [&](int b_) {
        f32x4 st[2][4] = {};
        __builtin_amdgcn_s_setprio(1);
#pragma unroll
        for (int j = 0; j < 4; ++j)
#pragma unroll
            for (int c = 0; c < 2; ++c) {
                bf16x8 kf = *reinterpret_cast<const bf16x8*>(
                    &Ks[b_][(j * 16 + lrow) * 64 + (((c * 64 + lhi * 16) ^ rsw) >> 1)]);
#pragma unroll
                for (int qfr = 0; qfr < 2; ++qfr)
                    st[qfr][j] = __builtin_amdgcn_mfma_f32_16x16x32_bf16(
                        kf, qf[qfr][c], st[qfr][j], 0, 0, 0);
            }
        __builtin_amdgcn_s_setprio(0);

        // softmax fully in-register: P packed as 16x16x16 B-operand fragments
        union { unsigned u[2]; s16x4 s; } pj[2][4];
#pragma unroll
        for (int qfr = 0; qfr < 2; ++qfr)
#pragma unroll
            for (int j = 0; j < 4; ++j) {
                float e0 = __builtin_amdgcn_exp2f(st[qfr][j][0]);
                float e1 = __builtin_amdgcn_exp2f(st[qfr][j][1]);
                float e2 = __builtin_amdgcn_exp2f(st[qfr][j][2]);
                float e3 = __builtin_amdgcn_exp2f(st[qfr][j][3]);
                lsum[qfr] += (e0 + e1) + (e2 + e3);
                pj[qfr][j].u[0] = pk2(e0, e1);
                pj[qfr][j].u[1] = pk2(e2, e3);
            }

        // PV: O^T = V^T * P^T via K=16 MFMA; one b128 V read = two key-blocks
        __builtin_amdgcn_s_setprio(1);
#pragma unroll
        for (int p = 0; p < 2; ++p)
#pragma unroll
            for (int f = 0; f < 4; ++f) {
                union { bf16x8 v; s16x4 h[2]; } vf;
                vf.v = *reinterpret_cast<const bf16x8*>(
                    &Vs[b_][(f * 16 + lrow) * 64 +
                            (((p * 64 + lhi * 16) ^ rsw) >> 1)]);
#pragma unroll
                for (int qfr = 0; qfr < 2; ++qfr) {
                    of[qfr][f] = __builtin_amdgcn_mfma_f32_16x16x16bf16_1k(
                        vf.h[0], pj[qfr][2 * p].s, of[qfr][f], 0, 0, 0);
                    of[qfr][f] = __builtin_amdgcn_mfma_f32_16x16x16bf16_1k(
                        vf.h[1], pj[qfr][2 * p + 1].s, of[qfr][f], 0, 0, 0);
                }
            }
        __builtin_amdgcn_s_setprio(0);
    };

    STAGE(0, 0);
    int cur = 0;
    for (int it = 0; it < NT; ++it) {
        if (it + 1 < NT) {
            STAGE(cur ^ 1, (it + 1) * KB);
            asm volatile("s_waitcnt vmcnt(2)" ::: "memory");  // cur's 2 landed
        } else {
            asm volatile("s_waitcnt vmcnt(0)" ::: "memory");
        }
        __builtin_amdgcn_s_barrier();
        __builtin_amdgcn_sched_barrier(0);
        COMPUTE(cur);
        __builtin_amdgcn_s_barrier();   // reads of cur done -> overwrite ok
        cur ^= 1;
    }

    // l reduce over lhi groups -> every lane holds l(q = lrow) per fragment
#pragma unroll
    for (int qfr = 0; qfr < 2; ++qfr) {
        lsum[qfr] += __shfl_xor(lsum[qfr], 16);
        lsum[qfr] += __shfl_xor(lsum[qfr], 32);
    }

    // epilogue: wave-private 32(s) x 64(d) transpose; waves 0-3 in Ks, 4-7 in Vs
    bf16* eb = (wid < 4) ? ((bf16*)Ks + wid * 2048) : ((bf16*)Vs + (wid - 4) * 2048);
#pragma unroll
    for (int qfr = 0; qfr < 2; ++qfr) {
        float inv = 1.0f / lsum[qfr];
        int srt = qfr * 16 + lrow;
#pragma unroll
        for (int f = 0; f < 4; ++f) {
            bf16x4 pk;
#pragma unroll
            for (int r = 0; r < 4; ++r) pk[r] = (bf16)(of[qfr][f][r] * inv);
            *reinterpret_cast<bf16x4*>(
                reinterpret_cast<char*>(eb) + srt * 128 +
                (((f * 16 + 4 * lhi) * 2) ^ ((srt & 7) << 4))) = pk;
        }
    }
    const int bb = bh >> 4, h = bh & 15;
#pragma unroll
    for (int it = 0; it < 4; ++it) {
        int rt = it * 8 + (lane >> 3);
        bf16x8 v = *reinterpret_cast<const bf16x8*>(
            reinterpret_cast<char*>(eb) + rt * 128 +
            (((lane & 7) * 16) ^ ((rt & 7) << 4)));
        int s = qw + rt;
        *reinterpret_cast<bf16x8*>(
            &Ao[((long)bb * NS + s) * ND + h * HD + (lane & 7) * 8]) = v;
    }
}

// ---------------- launch ----------------
extern "C" void kernel_launch(void* const* d_in, const int* in_sizes, int n_in,
                              void* d_out, int out_size, void* d_ws, size_t ws_size,
                              hipStream_t stream) {
    const float* x    = (const float*)d_in[0];
    const float* Wqkv = (const float*)d_in[1];
    const float* bqkv = (const float*)d_in[2];
    const float* Wout = (const float*)d_in[3];
    const float* bout = (const float*)d_in[4];
    float* out = (float*)d_out;

    char* ws = (char*)d_ws;
    bf16* Xb  = (bf16*)(ws);                         // 16.78 MB
    bf16* Wqt = (bf16*)(ws + 16777216);              //  6.29 MB
    bf16* Wot = (bf16*)(ws + 23068672);              //  2.10 MB
    bf16* Qb  = (bf16*)(ws + 25165824);              // 16.78 MB
    bf16* Kb  = (bf16*)(ws + 41943040);              // 16.78 MB
    bf16* Vt  = (bf16*)(ws + 58720256);              // 16.78 MB
    bf16* Ab  = (bf16*)(ws + 75497472);              // 16.78 MB  (total ~92 MB)

    k_conv<<<dim3(8192), dim3(256), 0, stream>>>(x, Xb, NB * NS * ND);
    k_transconv<<<dim3(96, 16), dim3(32, 8), 0, stream>>>(Wqkv, Wqt, ND, 3 * ND);
    k_transconv<<<dim3(32, 16), dim3(32, 8), 0, stream>>>(Wout, Wot, ND, ND);

    // merged QKV producer: 1536 blocks = 3 exact generations at 2/CU
    k_gemmQKV<<<dim3(24, 64), dim3(256), 0, stream>>>(
        Xb, Wqt, bqkv, Qb, Kb, Vt, ND);

    k_attn<<<dim3(8, 64), dim3(512), 0, stream>>>(Qb, Kb, Vt, Ab);

    k_gemmO<<<dim3(8, 64), dim3(256), 0, stream>>>(
        Ab, Wot, bout, out, ND);
}